// Round 1
// 376.713 us; speedup vs baseline: 1.0431x; 1.0431x over previous
//
#include <hip/hip_runtime.h>

// Problem constants (B=2, S=8192, IN=2048, OUT=2048, L=4, R=32)
#define M_DIM 16384
#define N_DIM 2048
#define K_DIM 2048
#define L_AD 4
#define R_AD 32

typedef __bf16 bf16_t;
typedef bf16_t bf16x8 __attribute__((ext_vector_type(8)));
typedef bf16_t bf16x4 __attribute__((ext_vector_type(4)));
typedef float f32x4 __attribute__((ext_vector_type(4)));

#define BM 128
#define BN 128
#define BK 64

__device__ __forceinline__ void async_load16(const void* g, void* l) {
  __builtin_amdgcn_global_load_lds(
      (const __attribute__((address_space(1))) unsigned int*)g,
      (__attribute__((address_space(3))) unsigned int*)l, 16, 0, 0);
}

// ---------------------------------------------------------------------------
// Kernel 0: x fp32 -> bf16 (33.5M elems). Pure bandwidth pass.
// ---------------------------------------------------------------------------
__global__ __launch_bounds__(256) void convert_x_kernel(
    const float* __restrict__ X, bf16_t* __restrict__ Xb) {
  const size_t base = ((size_t)blockIdx.x * 256 + threadIdx.x) * 8;
  f32x4 lo = *(const f32x4*)(X + base);
  f32x4 hi = *(const f32x4*)(X + base + 4);
  bf16x8 v;
  v[0] = (bf16_t)lo[0]; v[1] = (bf16_t)lo[1];
  v[2] = (bf16_t)lo[2]; v[3] = (bf16_t)lo[3];
  v[4] = (bf16_t)hi[0]; v[5] = (bf16_t)hi[1];
  v[6] = (bf16_t)hi[2]; v[7] = (bf16_t)hi[3];
  *(bf16x8*)(Xb + base) = v;
}

// ---------------------------------------------------------------------------
// Kernel 1: Weff[n,k] = bf16( W[n,k] + sum_l scale_l * sum_r ups[l,n,r]*downs[l,r,k] )
// ---------------------------------------------------------------------------
__global__ __launch_bounds__(256) void build_weff_kernel(
    const float* __restrict__ W, const float* __restrict__ downs,
    const float* __restrict__ ups, const float* __restrict__ scales,
    bf16_t* __restrict__ weff) {
  __shared__ float up_s[64 * 129];
  __shared__ float down_s[128 * 64];
  const int t = threadIdx.x;
  const int n0 = blockIdx.y * 64;
  const int k0 = blockIdx.x * 64;

  for (int l = 0; l < L_AD; ++l) {
    const float sc = scales[l];
    const float* up_l = ups + (size_t)l * N_DIM * R_AD;
    #pragma unroll
    for (int j = 0; j < 8; ++j) {
      int flat = j * 256 + t;
      int nl = flat >> 5, r = flat & 31;
      up_s[nl * 129 + l * 32 + r] = sc * up_l[(size_t)(n0 + nl) * R_AD + r];
    }
  }
  #pragma unroll
  for (int j = 0; j < 32; ++j) {
    int flat = j * 256 + t;
    int lr = flat >> 6, kk = flat & 63;
    down_s[lr * 64 + kk] = downs[(size_t)lr * K_DIM + k0 + kk];
  }
  __syncthreads();

  const int tn = t >> 4, tk = t & 15;
  float acc[4][4] = {};
  for (int lr = 0; lr < L_AD * R_AD; ++lr) {
    f32x4 b = *(const f32x4*)&down_s[lr * 64 + tk * 4];
    #pragma unroll
    for (int u = 0; u < 4; ++u) {
      float a = up_s[(tn * 4 + u) * 129 + lr];
      #pragma unroll
      for (int v = 0; v < 4; ++v) acc[u][v] += a * b[v];
    }
  }
  #pragma unroll
  for (int u = 0; u < 4; ++u) {
    int n = n0 + tn * 4 + u;
    f32x4 wv = *(const f32x4*)&W[(size_t)n * K_DIM + k0 + tk * 4];
    bf16x4 o;
    #pragma unroll
    for (int v = 0; v < 4; ++v) o[v] = (bf16_t)(acc[u][v] + wv[v]);
    *(bf16x4*)&weff[(size_t)n * K_DIM + k0 + tk * 4] = o;
  }
}

// ---------------------------------------------------------------------------
// Kernel 2 (fast path): 256x256 tile, BK=64, 8 waves (2Mx4N), 8-phase schedule
// with counted vmcnt (T3+T4), setprio around MFMA clusters (T5), XOR-chunk
// swizzled LDS (linear dest for global_load_lds, pre-swizzled source) and
// bijective XCD block swizzle (T1). Per-wave output 128x64 via 8x4 frags of
// mfma_f32_16x16x32_bf16.
//
// LDS: sm[buf(2)][op A/B(2)][16384 bf16] = 128 KiB.
//   Half h of a (256x64) tile = rows h*128..+127, stored as 1024 16B-chunks:
//   chunk d: row = d>>3, slot = d&7 holds global k-octet  c = slot ^ (row&7).
//
// Steady-state schedule, iteration j computes K-tiles {2j (buf0), 2j+1 (buf1)},
// reads: ph1 A(m0-3)+B(all) of buf0, ph3 A(m4-7) buf0, ph5/ph7 same on buf1.
// MFMA quadrants: ph1 m0-3xn0-1, ph2 m0-3xn2-3, ph3 m4-7xn2-3, ph4 m4-7xn0-1.
// Stages (1 half-tile = 2 global_load_lds/thread per phase):
//   ph1: buf1.A1<-k(2j+1)   [deferred; completes at ph4's vmcnt(6)]
//   ph2: buf0.B0<-2j+2  ph3: buf0.B1  ph4: buf0.A0  ph5: buf0.A1
//   ph6: buf1.B0<-2j+3  ph7: buf1.B1  ph8: buf1.A0
// vmcnt(6) only at ph4 and ph8. Every stage is issued >=1 barrier after the
// last ds_read of its region; every region is vmcnt-covered before first read.
// ---------------------------------------------------------------------------
#define BARRIER() __builtin_amdgcn_s_barrier()
#define LGKM0() asm volatile("s_waitcnt lgkmcnt(0)" ::: "memory")
#define VMCNT6() asm volatile("s_waitcnt vmcnt(6)" ::: "memory")

__global__ __launch_bounds__(512, 2) void gemm_bf16_256(
    const bf16_t* __restrict__ Xb, const bf16_t* __restrict__ Wb,
    const float* __restrict__ bias, float* __restrict__ out) {
  __shared__ __align__(16) bf16_t sm[2][2][16384];

  // bijective XCD swizzle: nwg=512 (%8==0); each XCD gets an 8x8 tile patch.
  const int orig = blockIdx.x;
  const int swz = (orig & 7) * 64 + (orig >> 3);
  const int m0 = (swz >> 3) * 256;
  const int n0 = (swz & 7) * 256;

  const int t = threadIdx.x;
  const int l = t & 63;
  const int w = t >> 6;
  const int wm = w >> 2, wn = w & 3;
  const int col = l & 15, quad = l >> 4;

  // staging geometry: thread stages chunks d0 and d0+512 of each half-tile
  const int d0 = w * 64 + l;
  const int row0 = d0 >> 3;
  const int c0 = (d0 & 7) ^ (row0 & 7);
  const bf16_t* Ab = Xb + (size_t)(m0 + row0) * K_DIM + c0 * 8;
  const bf16_t* Bb = Wb + (size_t)(n0 + row0) * K_DIM + c0 * 8;

  const int arow = wm * 128 + col;  // + f*16
  const int brow = wn * 64 + col;   // + g*16

  float bn[4];
  #pragma unroll
  for (int g = 0; g < 4; ++g) bn[g] = bias[n0 + wn * 64 + g * 16 + col];

  f32x4 acc[8][4] = {};
  bf16x8 aA[4][2], bB[4][2];

#define STG(Gb, B_, OP, H, KT)                                                 \
  do {                                                                         \
    async_load16((Gb) + ((size_t)(H)*128) * K_DIM + (size_t)(KT)*64,           \
                 &sm[B_][OP][(H)*8192 + d0 * 8]);                              \
    async_load16((Gb) + ((size_t)(H)*128 + 64) * K_DIM + (size_t)(KT)*64,      \
                 &sm[B_][OP][(H)*8192 + (d0 + 512) * 8]);                      \
  } while (0)

#define LDA(F0, B_)                                                            \
  do {                                                                         \
    _Pragma("unroll") for (int f_ = 0; f_ < 4; ++f_) {                         \
      const int R_ = arow + ((F0) + f_) * 16;                                  \
      const int rl_ = R_ & 127, h_ = R_ >> 7;                                  \
      _Pragma("unroll") for (int ks_ = 0; ks_ < 2; ++ks_) {                    \
        const int sl_ = (ks_ * 4 + quad) ^ (rl_ & 7);                          \
        aA[f_][ks_] =                                                          \
            *(const bf16x8*)&sm[B_][0][h_ * 8192 + (rl_ * 8 + sl_) * 8];       \
      }                                                                        \
    }                                                                          \
  } while (0)

#define LDB(B_)                                                                \
  do {                                                                         \
    _Pragma("unroll") for (int g_ = 0; g_ < 4; ++g_) {                         \
      const int R_ = brow + g_ * 16;                                           \
      const int rl_ = R_ & 127, h_ = R_ >> 7;                                  \
      _Pragma("unroll") for (int ks_ = 0; ks_ < 2; ++ks_) {                    \
        const int sl_ = (ks_ * 4 + quad) ^ (rl_ & 7);                          \
        bB[g_][ks_] =                                                          \
            *(const bf16x8*)&sm[B_][1][h_ * 8192 + (rl_ * 8 + sl_) * 8];       \
      }                                                                        \
    }                                                                          \
  } while (0)

#define MF(FA, G0)                                                             \
  do {                                                                         \
    __builtin_amdgcn_s_setprio(1);                                             \
    _Pragma("unroll") for (int f_ = 0; f_ < 4; ++f_)                           \
        _Pragma("unroll") for (int g_ = 0; g_ < 2; ++g_)                       \
            _Pragma("unroll") for (int ks_ = 0; ks_ < 2; ++ks_)                \
                acc[(FA) + f_][(G0) + g_] =                                    \
                    __builtin_amdgcn_mfma_f32_16x16x32_bf16(                   \
                        aA[f_][ks_], bB[(G0) + g_][ks_],                       \
                        acc[(FA) + f_][(G0) + g_], 0, 0, 0);                   \
    __builtin_amdgcn_s_setprio(0);                                             \
  } while (0)

  // Prologue: K-tile 0 -> buf0 (all 4 halves), K-tile 1 -> buf1 (B0,B1,A0).
  // vmcnt(6) leaves the newest 3 halves in flight; buf0's 8 loads complete.
  STG(Bb, 0, 1, 0, 0); STG(Bb, 0, 1, 1, 0);
  STG(Ab, 0, 0, 0, 0); STG(Ab, 0, 0, 1, 0);
  STG(Bb, 1, 1, 0, 1); STG(Bb, 1, 1, 1, 1);
  STG(Ab, 1, 0, 0, 1);
  VMCNT6();
  BARRIER();

  for (int j = 0; j < 16; ++j) {
    const int k1 = 2 * j + 1;
    const int kt2 = (2 * j + 2 < 32) ? 2 * j + 2 : 31;  // clamped tail stages
    const int kt3 = (2 * j + 3 < 32) ? 2 * j + 3 : 31;  // (loads valid, unused)

    // ph1: read buf0 A(m0-3)+B(all); stage buf1.A1 (K-tile 2j+1, late half)
    LDA(0, 0); LDB(0);
    STG(Ab, 1, 0, 1, k1);
    BARRIER(); LGKM0();
    MF(0, 0);
    BARRIER();
    // ph2
    STG(Bb, 0, 1, 0, kt2);
    BARRIER(); LGKM0();
    MF(0, 2);
    BARRIER();
    // ph3: read buf0 A(m4-7)
    LDA(4, 0);
    STG(Bb, 0, 1, 1, kt2);
    BARRIER(); LGKM0();
    MF(4, 2);
    BARRIER();
    // ph4: counted wait -> buf1's K-tile (2j+1) fully resident for ph5
    STG(Ab, 0, 0, 0, kt2);
    BARRIER(); LGKM0();
    MF(4, 0);
    VMCNT6();
    BARRIER();
    // ph5: read buf1 A(m0-3)+B(all)
    LDA(0, 1); LDB(1);
    STG(Ab, 0, 0, 1, kt2);
    BARRIER(); LGKM0();
    MF(0, 0);
    BARRIER();
    // ph6
    STG(Bb, 1, 1, 0, kt3);
    BARRIER(); LGKM0();
    MF(0, 2);
    BARRIER();
    // ph7: read buf1 A(m4-7)
    LDA(4, 1);
    STG(Bb, 1, 1, 1, kt3);
    BARRIER(); LGKM0();
    MF(4, 2);
    BARRIER();
    // ph8: counted wait -> buf0's K-tile (2j+2) fully resident for next ph1
    STG(Ab, 1, 0, 0, kt3);
    BARRIER(); LGKM0();
    MF(4, 0);
    VMCNT6();
    BARRIER();
  }

  // epilogue: C/D layout col=lane&15, row=quad*4+r per 16x16 frag
  #pragma unroll
  for (int f = 0; f < 8; ++f) {
    const int m = m0 + wm * 128 + f * 16 + quad * 4;
    #pragma unroll
    for (int g = 0; g < 4; ++g) {
      const int n = n0 + wn * 64 + g * 16 + col;
      float* op = out + (size_t)m * N_DIM + n;
      #pragma unroll
      for (int r = 0; r < 4; ++r) op[(size_t)r * N_DIM] = acc[f][g][r] + bn[g];
    }
  }
#undef STG
#undef LDA
#undef LDB
#undef MF
}

// ---------------------------------------------------------------------------
// Fallback GEMM (R1 version): fp32 A converted in-kernel. Used if ws too small.
// ---------------------------------------------------------------------------
#define SA 72
__global__ __launch_bounds__(256) void lora_gemm_fallback(
    const float* __restrict__ X, const bf16_t* __restrict__ Wb,
    const float* __restrict__ bias, float* __restrict__ out) {
  __shared__ __align__(16) bf16_t As[BM * SA];
  __shared__ __align__(16) bf16_t Bs[BN * BK];

  const int t = threadIdx.x;
  const int lane = t & 63;
  const int wv = t >> 6;
  const int wm = wv >> 1, wn = wv & 1;
  const int col = lane & 15, quad = lane >> 4;
  const int m0 = blockIdx.y * BM;
  const int n0 = blockIdx.x * BN;
  const int srow = t >> 3;
  const int soct = t & 7;

  f32x4 acc[4][4] = {};
  float bn[4];
  #pragma unroll
  for (int j = 0; j < 4; ++j) bn[j] = bias[n0 + wn * 64 + j * 16 + col];

  for (int kt = 0; kt < K_DIM / BK; ++kt) {
    const int kg = kt * BK;
    #pragma unroll
    for (int j = 0; j < 4; ++j) {
      int n = j * 32 + srow;
      int c = soct ^ (n & 7);
      async_load16(Wb + (size_t)(n0 + n) * K_DIM + kg + c * 8,
                   &Bs[(size_t)(j * 256 + t) * 8]);
    }
    #pragma unroll
    for (int j = 0; j < 4; ++j) {
      int m = j * 32 + srow;
      const f32x4* src = (const f32x4*)(X + (size_t)(m0 + m) * K_DIM + kg + soct * 8);
      f32x4 lo = src[0], hi = src[1];
      bf16x8 v;
      v[0] = (bf16_t)lo[0]; v[1] = (bf16_t)lo[1];
      v[2] = (bf16_t)lo[2]; v[3] = (bf16_t)lo[3];
      v[4] = (bf16_t)hi[0]; v[5] = (bf16_t)hi[1];
      v[6] = (bf16_t)hi[2]; v[7] = (bf16_t)hi[3];
      *(bf16x8*)&As[m * SA + soct * 8] = v;
    }
    __syncthreads();

    #pragma unroll
    for (int ks = 0; ks < 2; ++ks) {
      bf16x8 af[4], bfr[4];
      #pragma unroll
      for (int i = 0; i < 4; ++i)
        af[i] = *(const bf16x8*)&As[(wm * 64 + i * 16 + col) * SA + ks * 32 + quad * 8];
      #pragma unroll
      for (int j = 0; j < 4; ++j) {
        int n = wn * 64 + j * 16 + col;
        int p = (ks * 4 + quad) ^ (n & 7);
        bfr[j] = *(const bf16x8*)&Bs[n * BK + p * 8];
      }
      #pragma unroll
      for (int i = 0; i < 4; ++i) {
        #pragma unroll
        for (int j = 0; j < 4; ++j)
          acc[i][j] = __builtin_amdgcn_mfma_f32_16x16x32_bf16(af[i], bfr[j], acc[i][j], 0, 0, 0);
      }
    }
    __syncthreads();
  }

  #pragma unroll
  for (int i = 0; i < 4; ++i) {
    #pragma unroll
    for (int r = 0; r < 4; ++r) {
      int m = m0 + wm * 64 + i * 16 + quad * 4 + r;
      float* orow = out + (size_t)m * N_DIM + n0 + wn * 64 + col;
      #pragma unroll
      for (int j = 0; j < 4; ++j)
        orow[j * 16] = acc[i][j][r] + bn[j];
    }
  }
}

extern "C" void kernel_launch(void* const* d_in, const int* in_sizes, int n_in,
                              void* d_out, int out_size, void* d_ws, size_t ws_size,
                              hipStream_t stream) {
  const float* x      = (const float*)d_in[0];
  const float* weight = (const float*)d_in[1];
  const float* bias   = (const float*)d_in[2];
  const float* downs  = (const float*)d_in[3];
  const float* ups    = (const float*)d_in[4];
  const float* scales = (const float*)d_in[5];
  float* out = (float*)d_out;

  const size_t weff_bytes = (size_t)N_DIM * K_DIM * 2;            // 8.4 MB
  const size_t xb_bytes   = (size_t)M_DIM * K_DIM * 2;            // 67 MB
  bf16_t* weff = (bf16_t*)d_ws;

  dim3 g1(K_DIM / 64, N_DIM / 64);
  build_weff_kernel<<<g1, 256, 0, stream>>>(weight, downs, ups, scales, weff);

  if (ws_size >= weff_bytes + xb_bytes) {
    bf16_t* xb = (bf16_t*)((char*)d_ws + weff_bytes);
    const size_t n_elem = (size_t)M_DIM * K_DIM;
    convert_x_kernel<<<(unsigned)(n_elem / (256 * 8)), 256, 0, stream>>>(x, xb);
    gemm_bf16_256<<<dim3((M_DIM / 256) * (N_DIM / 256)), 512, 0, stream>>>(
        xb, weff, bias, out);
  } else {
    dim3 g2(N_DIM / BN, M_DIM / BM);
    lora_gemm_fallback<<<g2, 256, 0, stream>>>(x, weff, bias, out);
  }
}

// Round 2
// 367.194 us; speedup vs baseline: 1.0702x; 1.0259x over previous
//
#include <hip/hip_runtime.h>

// Problem constants (B=2, S=8192, IN=2048, OUT=2048, L=4, R=32)
#define M_DIM 16384
#define N_DIM 2048
#define K_DIM 2048
#define L_AD 4
#define R_AD 32

typedef __bf16 bf16_t;
typedef bf16_t bf16x8 __attribute__((ext_vector_type(8)));
typedef bf16_t bf16x4 __attribute__((ext_vector_type(4)));
typedef float f32x4 __attribute__((ext_vector_type(4)));

#define BM 128
#define BN 128
#define BK 64

__device__ __forceinline__ void async_load16(const void* g, void* l) {
  __builtin_amdgcn_global_load_lds(
      (const __attribute__((address_space(1))) unsigned int*)g,
      (__attribute__((address_space(3))) unsigned int*)l, 16, 0, 0);
}

// ---------------------------------------------------------------------------
// Kernel 0: x fp32 -> bf16 (33.5M elems). Pure bandwidth pass.
// ---------------------------------------------------------------------------
__global__ __launch_bounds__(256) void convert_x_kernel(
    const float* __restrict__ X, bf16_t* __restrict__ Xb) {
  const size_t base = ((size_t)blockIdx.x * 256 + threadIdx.x) * 8;
  f32x4 lo = *(const f32x4*)(X + base);
  f32x4 hi = *(const f32x4*)(X + base + 4);
  bf16x8 v;
  v[0] = (bf16_t)lo[0]; v[1] = (bf16_t)lo[1];
  v[2] = (bf16_t)lo[2]; v[3] = (bf16_t)lo[3];
  v[4] = (bf16_t)hi[0]; v[5] = (bf16_t)hi[1];
  v[6] = (bf16_t)hi[2]; v[7] = (bf16_t)hi[3];
  *(bf16x8*)(Xb + base) = v;
}

// ---------------------------------------------------------------------------
// Kernel 1: Weff[n,k] = bf16( W[n,k] + sum_l scale_l * sum_r ups[l,n,r]*downs[l,r,k] )
// ---------------------------------------------------------------------------
__global__ __launch_bounds__(256) void build_weff_kernel(
    const float* __restrict__ W, const float* __restrict__ downs,
    const float* __restrict__ ups, const float* __restrict__ scales,
    bf16_t* __restrict__ weff) {
  __shared__ float up_s[64 * 129];
  __shared__ float down_s[128 * 64];
  const int t = threadIdx.x;
  const int n0 = blockIdx.y * 64;
  const int k0 = blockIdx.x * 64;

  for (int l = 0; l < L_AD; ++l) {
    const float sc = scales[l];
    const float* up_l = ups + (size_t)l * N_DIM * R_AD;
    #pragma unroll
    for (int j = 0; j < 8; ++j) {
      int flat = j * 256 + t;
      int nl = flat >> 5, r = flat & 31;
      up_s[nl * 129 + l * 32 + r] = sc * up_l[(size_t)(n0 + nl) * R_AD + r];
    }
  }
  #pragma unroll
  for (int j = 0; j < 32; ++j) {
    int flat = j * 256 + t;
    int lr = flat >> 6, kk = flat & 63;
    down_s[lr * 64 + kk] = downs[(size_t)lr * K_DIM + k0 + kk];
  }
  __syncthreads();

  const int tn = t >> 4, tk = t & 15;
  float acc[4][4] = {};
  for (int lr = 0; lr < L_AD * R_AD; ++lr) {
    f32x4 b = *(const f32x4*)&down_s[lr * 64 + tk * 4];
    #pragma unroll
    for (int u = 0; u < 4; ++u) {
      float a = up_s[(tn * 4 + u) * 129 + lr];
      #pragma unroll
      for (int v = 0; v < 4; ++v) acc[u][v] += a * b[v];
    }
  }
  #pragma unroll
  for (int u = 0; u < 4; ++u) {
    int n = n0 + tn * 4 + u;
    f32x4 wv = *(const f32x4*)&W[(size_t)n * K_DIM + k0 + tk * 4];
    bf16x4 o;
    #pragma unroll
    for (int v = 0; v < 4; ++v) o[v] = (bf16_t)(acc[u][v] + wv[v]);
    *(bf16x4*)&weff[(size_t)n * K_DIM + k0 + tk * 4] = o;
  }
}

// ---------------------------------------------------------------------------
// Kernel 2 (fast path): 256x256 tile, BK=64, 8 waves (2Mx4N), 8-phase schedule
// with counted vmcnt (T3+T4), setprio around MFMA clusters (T5), XOR-chunk
// swizzled LDS (linear dest for global_load_lds, pre-swizzled source) and
// bijective XCD block swizzle (T1).
//
// R2 change vs R1: ds_reads moved INSIDE the barrier pair (after barrier1,
// pinned by sched_barrier(0)), no manual lgkmcnt(0) -- the compiler emits
// fine-grained lgkmcnt between each read and its consuming MFMA, so read
// return overlaps the MFMA cluster instead of serializing ahead of it.
// Read distribution rebalanced 16/0/8/0 -> 12/4/8/0 per K-tile by splitting
// the B-frag reads across ph1/ph2 (no extra reads, same registers).
//
// LDS: sm[buf(2)][op A/B(2)][16384 bf16] = 128 KiB.
//   Half h of a (256x64) tile = rows h*128..+127, stored as 1024 16B-chunks:
//   chunk d: row = d>>3, slot = d&7 holds global k-octet  c = slot ^ (row&7).
//
// Stages (1 half-tile = 2 global_load_lds/thread per phase):
//   ph1: buf1.A1<-k(2j+1)   [completes at ph4's vmcnt(6)]
//   ph2: buf0.B0<-2j+2  ph3: buf0.B1  ph4: buf0.A0  ph5: buf0.A1
//   ph6: buf1.B0<-2j+3  ph7: buf1.B1  ph8: buf1.A0
// vmcnt(6) only at ph4 and ph8. Every stage is issued >=1 barrier after the
// last ds_read of its region (reads complete before their in-phase MFMA
// consumers, hence before barrier2); every region is vmcnt+barrier covered
// before first read.
// ---------------------------------------------------------------------------
#define BARRIER() __builtin_amdgcn_s_barrier()
#define SCHEDB() __builtin_amdgcn_sched_barrier(0)
#define VMCNT6() asm volatile("s_waitcnt vmcnt(6)" ::: "memory")

__global__ __launch_bounds__(512, 2) void gemm_bf16_256(
    const bf16_t* __restrict__ Xb, const bf16_t* __restrict__ Wb,
    const float* __restrict__ bias, float* __restrict__ out) {
  __shared__ __align__(16) bf16_t sm[2][2][16384];

  // bijective XCD swizzle: nwg=512 (%8==0); each XCD gets an 8x8 tile patch.
  const int orig = blockIdx.x;
  const int swz = (orig & 7) * 64 + (orig >> 3);
  const int m0 = (swz >> 3) * 256;
  const int n0 = (swz & 7) * 256;

  const int t = threadIdx.x;
  const int l = t & 63;
  const int w = t >> 6;
  const int wm = w >> 2, wn = w & 3;
  const int col = l & 15, quad = l >> 4;

  // staging geometry: thread stages chunks d0 and d0+512 of each half-tile
  const int d0 = w * 64 + l;
  const int row0 = d0 >> 3;
  const int c0 = (d0 & 7) ^ (row0 & 7);
  const bf16_t* Ab = Xb + (size_t)(m0 + row0) * K_DIM + c0 * 8;
  const bf16_t* Bb = Wb + (size_t)(n0 + row0) * K_DIM + c0 * 8;

  const int arow = wm * 128 + col;  // + f*16
  const int brow = wn * 64 + col;   // + g*16

  float bn[4];
  #pragma unroll
  for (int g = 0; g < 4; ++g) bn[g] = bias[n0 + wn * 64 + g * 16 + col];

  f32x4 acc[8][4] = {};
  bf16x8 aA[4][2], bB[4][2];

#define STG(Gb, B_, OP, H, KT)                                                 \
  do {                                                                         \
    async_load16((Gb) + ((size_t)(H)*128) * K_DIM + (size_t)(KT)*64,           \
                 &sm[B_][OP][(H)*8192 + d0 * 8]);                              \
    async_load16((Gb) + ((size_t)(H)*128 + 64) * K_DIM + (size_t)(KT)*64,      \
                 &sm[B_][OP][(H)*8192 + (d0 + 512) * 8]);                      \
  } while (0)

// read one A row-frag (both k-slices) into aA[fi]
#define RDA(fi, F0, B_)                                                        \
  do {                                                                         \
    const int R_ = arow + ((F0) + (fi)) * 16;                                  \
    const int rl_ = R_ & 127, h_ = R_ >> 7;                                    \
    _Pragma("unroll") for (int ks_ = 0; ks_ < 2; ++ks_) {                      \
      const int sl_ = (ks_ * 4 + quad) ^ (rl_ & 7);                            \
      aA[fi][ks_] =                                                            \
          *(const bf16x8*)&sm[B_][0][h_ * 8192 + (rl_ * 8 + sl_) * 8];         \
    }                                                                          \
  } while (0)

// read one B col-frag (both k-slices) into bB[gi]
#define RDB(gi, B_)                                                            \
  do {                                                                         \
    const int R_ = brow + (gi) * 16;                                           \
    const int rl_ = R_ & 127, h_ = R_ >> 7;                                    \
    _Pragma("unroll") for (int ks_ = 0; ks_ < 2; ++ks_) {                      \
      const int sl_ = (ks_ * 4 + quad) ^ (rl_ & 7);                            \
      bB[gi][ks_] =                                                            \
          *(const bf16x8*)&sm[B_][1][h_ * 8192 + (rl_ * 8 + sl_) * 8];         \
    }                                                                          \
  } while (0)

#define MF(FA, G0)                                                             \
  do {                                                                         \
    __builtin_amdgcn_s_setprio(1);                                             \
    _Pragma("unroll") for (int f_ = 0; f_ < 4; ++f_)                           \
        _Pragma("unroll") for (int g_ = 0; g_ < 2; ++g_)                       \
            _Pragma("unroll") for (int ks_ = 0; ks_ < 2; ++ks_)                \
                acc[(FA) + f_][(G0) + g_] =                                    \
                    __builtin_amdgcn_mfma_f32_16x16x32_bf16(                   \
                        aA[f_][ks_], bB[(G0) + g_][ks_],                       \
                        acc[(FA) + f_][(G0) + g_], 0, 0, 0);                   \
    __builtin_amdgcn_s_setprio(0);                                             \
  } while (0)

  // Prologue: K-tile 0 -> buf0 (all 4 halves), K-tile 1 -> buf1 (B0,B1,A0).
  // vmcnt(6) leaves the newest 3 halves in flight; buf0's 8 loads complete.
  STG(Bb, 0, 1, 0, 0); STG(Bb, 0, 1, 1, 0);
  STG(Ab, 0, 0, 0, 0); STG(Ab, 0, 0, 1, 0);
  STG(Bb, 1, 1, 0, 1); STG(Bb, 1, 1, 1, 1);
  STG(Ab, 1, 0, 0, 1);
  VMCNT6();
  BARRIER();

  for (int j = 0; j < 16; ++j) {
    const int k1 = 2 * j + 1;
    const int kt2 = (2 * j + 2 < 32) ? 2 * j + 2 : 31;  // clamped tail stages
    const int kt3 = (2 * j + 3 < 32) ? 2 * j + 3 : 31;  // (loads valid, unused)

    // ph1: stage buf1.A1(k 2j+1); read buf0 A(m0-3)+B(n0-1); MFMA m0-3 x n0-1
    STG(Ab, 1, 0, 1, k1);
    BARRIER(); SCHEDB();
    RDA(0, 0, 0); RDB(0, 0); RDB(1, 0);
    RDA(1, 0, 0); RDA(2, 0, 0); RDA(3, 0, 0);
    MF(0, 0);
    SCHEDB(); BARRIER();
    // ph2: read buf0 B(n2-3); MFMA m0-3 x n2-3
    STG(Bb, 0, 1, 0, kt2);
    BARRIER(); SCHEDB();
    RDB(2, 0); RDB(3, 0);
    MF(0, 2);
    SCHEDB(); BARRIER();
    // ph3: read buf0 A(m4-7); MFMA m4-7 x n2-3
    STG(Bb, 0, 1, 1, kt2);
    BARRIER(); SCHEDB();
    RDA(0, 4, 0); RDA(1, 4, 0); RDA(2, 4, 0); RDA(3, 4, 0);
    MF(4, 2);
    SCHEDB(); BARRIER();
    // ph4: no reads; MFMA m4-7 x n0-1; counted wait -> buf1 K-tile resident
    STG(Ab, 0, 0, 0, kt2);
    BARRIER(); SCHEDB();
    MF(4, 0);
    VMCNT6();
    BARRIER();
    // ph5: read buf1 A(m0-3)+B(n0-1)
    STG(Ab, 0, 0, 1, kt2);
    BARRIER(); SCHEDB();
    RDA(0, 0, 1); RDB(0, 1); RDB(1, 1);
    RDA(1, 0, 1); RDA(2, 0, 1); RDA(3, 0, 1);
    MF(0, 0);
    SCHEDB(); BARRIER();
    // ph6: read buf1 B(n2-3)
    STG(Bb, 1, 1, 0, kt3);
    BARRIER(); SCHEDB();
    RDB(2, 1); RDB(3, 1);
    MF(0, 2);
    SCHEDB(); BARRIER();
    // ph7: read buf1 A(m4-7)
    STG(Bb, 1, 1, 1, kt3);
    BARRIER(); SCHEDB();
    RDA(0, 4, 1); RDA(1, 4, 1); RDA(2, 4, 1); RDA(3, 4, 1);
    MF(4, 2);
    SCHEDB(); BARRIER();
    // ph8: no reads; counted wait -> buf0's K-tile (2j+2) resident for ph1
    STG(Ab, 1, 0, 0, kt3);
    BARRIER(); SCHEDB();
    MF(4, 0);
    VMCNT6();
    BARRIER();
  }

  // epilogue: C/D layout col=lane&15, row=quad*4+r per 16x16 frag
  #pragma unroll
  for (int f = 0; f < 8; ++f) {
    const int m = m0 + wm * 128 + f * 16 + quad * 4;
    #pragma unroll
    for (int g = 0; g < 4; ++g) {
      const int n = n0 + wn * 64 + g * 16 + col;
      float* op = out + (size_t)m * N_DIM + n;
      #pragma unroll
      for (int r = 0; r < 4; ++r) op[(size_t)r * N_DIM] = acc[f][g][r] + bn[g];
    }
  }
#undef STG
#undef RDA
#undef RDB
#undef MF
}

// ---------------------------------------------------------------------------
// Fallback GEMM (R1 version): fp32 A converted in-kernel. Used if ws too small.
// ---------------------------------------------------------------------------
#define SA 72
__global__ __launch_bounds__(256) void lora_gemm_fallback(
    const float* __restrict__ X, const bf16_t* __restrict__ Wb,
    const float* __restrict__ bias, float* __restrict__ out) {
  __shared__ __align__(16) bf16_t As[BM * SA];
  __shared__ __align__(16) bf16_t Bs[BN * BK];

  const int t = threadIdx.x;
  const int lane = t & 63;
  const int wv = t >> 6;
  const int wm = wv >> 1, wn = wv & 1;
  const int col = lane & 15, quad = lane >> 4;
  const int m0 = blockIdx.y * BM;
  const int n0 = blockIdx.x * BN;
  const int srow = t >> 3;
  const int soct = t & 7;

  f32x4 acc[4][4] = {};
  float bn[4];
  #pragma unroll
  for (int j = 0; j < 4; ++j) bn[j] = bias[n0 + wn * 64 + j * 16 + col];

  for (int kt = 0; kt < K_DIM / BK; ++kt) {
    const int kg = kt * BK;
    #pragma unroll
    for (int j = 0; j < 4; ++j) {
      int n = j * 32 + srow;
      int c = soct ^ (n & 7);
      async_load16(Wb + (size_t)(n0 + n) * K_DIM + kg + c * 8,
                   &Bs[(size_t)(j * 256 + t) * 8]);
    }
    #pragma unroll
    for (int j = 0; j < 4; ++j) {
      int m = j * 32 + srow;
      const f32x4* src = (const f32x4*)(X + (size_t)(m0 + m) * K_DIM + kg + soct * 8);
      f32x4 lo = src[0], hi = src[1];
      bf16x8 v;
      v[0] = (bf16_t)lo[0]; v[1] = (bf16_t)lo[1];
      v[2] = (bf16_t)lo[2]; v[3] = (bf16_t)lo[3];
      v[4] = (bf16_t)hi[0]; v[5] = (bf16_t)hi[1];
      v[6] = (bf16_t)hi[2]; v[7] = (bf16_t)hi[3];
      *(bf16x8*)&As[m * SA + soct * 8] = v;
    }
    __syncthreads();

    #pragma unroll
    for (int ks = 0; ks < 2; ++ks) {
      bf16x8 af[4], bfr[4];
      #pragma unroll
      for (int i = 0; i < 4; ++i)
        af[i] = *(const bf16x8*)&As[(wm * 64 + i * 16 + col) * SA + ks * 32 + quad * 8];
      #pragma unroll
      for (int j = 0; j < 4; ++j) {
        int n = wn * 64 + j * 16 + col;
        int p = (ks * 4 + quad) ^ (n & 7);
        bfr[j] = *(const bf16x8*)&Bs[n * BK + p * 8];
      }
      #pragma unroll
      for (int i = 0; i < 4; ++i) {
        #pragma unroll
        for (int j = 0; j < 4; ++j)
          acc[i][j] = __builtin_amdgcn_mfma_f32_16x16x32_bf16(af[i], bfr[j], acc[i][j], 0, 0, 0);
      }
    }
    __syncthreads();
  }

  #pragma unroll
  for (int i = 0; i < 4; ++i) {
    #pragma unroll
    for (int r = 0; r < 4; ++r) {
      int m = m0 + wm * 64 + i * 16 + quad * 4 + r;
      float* orow = out + (size_t)m * N_DIM + n0 + wn * 64 + col;
      #pragma unroll
      for (int j = 0; j < 4; ++j)
        orow[j * 16] = acc[i][j][r] + bn[j];
    }
  }
}

extern "C" void kernel_launch(void* const* d_in, const int* in_sizes, int n_in,
                              void* d_out, int out_size, void* d_ws, size_t ws_size,
                              hipStream_t stream) {
  const float* x      = (const float*)d_in[0];
  const float* weight = (const float*)d_in[1];
  const float* bias   = (const float*)d_in[2];
  const float* downs  = (const float*)d_in[3];
  const float* ups    = (const float*)d_in[4];
  const float* scales = (const float*)d_in[5];
  float* out = (float*)d_out;

  const size_t weff_bytes = (size_t)N_DIM * K_DIM * 2;            // 8.4 MB
  const size_t xb_bytes   = (size_t)M_DIM * K_DIM * 2;            // 67 MB
  bf16_t* weff = (bf16_t*)d_ws;

  dim3 g1(K_DIM / 64, N_DIM / 64);
  build_weff_kernel<<<g1, 256, 0, stream>>>(weight, downs, ups, scales, weff);

  if (ws_size >= weff_bytes + xb_bytes) {
    bf16_t* xb = (bf16_t*)((char*)d_ws + weff_bytes);
    const size_t n_elem = (size_t)M_DIM * K_DIM;
    convert_x_kernel<<<(unsigned)(n_elem / (256 * 8)), 256, 0, stream>>>(x, xb);
    gemm_bf16_256<<<dim3((M_DIM / 256) * (N_DIM / 256)), 512, 0, stream>>>(
        xb, weff, bias, out);
  } else {
    dim3 g2(N_DIM / BN, M_DIM / BM);
    lora_gemm_fallback<<<g2, 256, 0, stream>>>(x, weff, bias, out);
  }
}